// Round 1
// baseline (115.840 us; speedup 1.0000x reference)
//
#include <hip/hip_runtime.h>
#include <stdint.h>
#include <math.h>

#define NPIX   16384
#define SAMPLE 1024
#define NV     778
#define BATCH  64

#define A_SCALE (1.0f / (float)(BATCH * SAMPLE))
#define B_SCALE (1.0f / (float)(BATCH * NV))

// ---------------------------------------------------------------------------
// Threefry-2x32, 20 rounds — matches jax._src.prng lowering exactly.
// ---------------------------------------------------------------------------
__device__ __forceinline__ uint32_t rotl32(uint32_t v, int r) {
  return (v << r) | (v >> (32 - r));
}

__device__ __forceinline__ uint32_t threefry_bits(uint32_t g) {
  // key(1) = (0,1); partitionable path: x0 = counts_hi = 0, x1 = g; out h0^h1.
  uint32_t ks0 = 0u, ks1 = 1u;
  uint32_t ks2 = ks0 ^ ks1 ^ 0x1BD11BDAu;
  uint32_t x0 = 0u + ks0, x1 = g + ks1;
#define TF_R(r) { x0 += x1; x1 = rotl32(x1, (r)); x1 ^= x0; }
  TF_R(13) TF_R(15) TF_R(26) TF_R(6)
  x0 += ks1; x1 += ks2 + 1u;
  TF_R(17) TF_R(29) TF_R(16) TF_R(24)
  x0 += ks2; x1 += ks0 + 2u;
  TF_R(13) TF_R(15) TF_R(26) TF_R(6)
  x0 += ks0; x1 += ks1 + 3u;
  TF_R(17) TF_R(29) TF_R(16) TF_R(24)
  x0 += ks1; x1 += ks2 + 4u;
  TF_R(13) TF_R(15) TF_R(26) TF_R(6)
  x0 += ks2; x1 += ks0 + 5u;
#undef TF_R
  return x0 ^ x1;
}

__device__ __forceinline__ float waveReduceSum(float v) {
#pragma unroll
  for (int off = 32; off > 0; off >>= 1) v += __shfl_down(v, off, 64);
  return v;
}

// ---------------------------------------------------------------------------
// K1 (fused score+select): one block per batch. Threefry u-bits computed
// in-register (gumbel is strictly monotone in u-bits; float-gumbel min-step
// >= e*2^-23 exceeds rounding error, so (ubits, lower-index) ordering ==
// JAX's top_k of float gumbels). Single uniform 512-bucket histogram +
// wave suffix scan + rank-select on boundary bucket. Emits normalized xyz.
// Block 0 / tid 0 also zeroes the loss accumulator (replaces the
// hipMemsetAsync dispatch; same-stream ordering makes it visible to K2).
// ---------------------------------------------------------------------------
__global__ __launch_bounds__(1024) void select_kernel(
    const float4* __restrict__ real4,
    const float* __restrict__ center,
    const float* __restrict__ M,
    const float* __restrict__ cube,
    float4* __restrict__ pcl4,
    float* __restrict__ out) {
  const int b = blockIdx.x;
  const int tid = threadIdx.x;
  const int lane = tid & 63;
  const int wv = tid >> 6;

  if (b == 0 && tid == 0) out[0] = 0.0f;

  __shared__ uint32_t hist[512];
  __shared__ uint32_t wt[8], offs[8];
  __shared__ uint64_t cand[512];
  __shared__ float candrv[512];
  __shared__ float sh_minv[6], sh_c[3], sh_hb[3];
  __shared__ uint32_t sh_cnt, sh_ccnt, sh_bstar, sh_above;

  if (tid == 0) {
    const float* m = M + (size_t)b * 9;
    float m00=m[0], m01=m[1], m02=m[2];
    float m10=m[3], m11=m[4], m12=m[5];
    float m20=m[6], m21=m[7], m22=m[8];
    float c00 = m11*m22 - m12*m21;
    float c10 = m12*m20 - m10*m22;
    float c20 = m10*m21 - m11*m20;
    float det = m00*c00 + m01*c10 + m02*c20;
    float id = 1.0f / det;
    sh_minv[0] = c00 * id;
    sh_minv[1] = (m02*m21 - m01*m22) * id;
    sh_minv[2] = (m01*m12 - m02*m11) * id;
    sh_minv[3] = c10 * id;
    sh_minv[4] = (m00*m22 - m02*m20) * id;
    sh_minv[5] = (m02*m10 - m00*m12) * id;
    sh_c[0] = center[b*3+0]; sh_c[1] = center[b*3+1]; sh_c[2] = center[b*3+2];
    sh_hb[0] = cube[b*3+0]*0.5f; sh_hb[1] = cube[b*3+1]*0.5f; sh_hb[2] = cube[b*3+2]*0.5f;
    sh_cnt = 0; sh_ccnt = 0;
  }
  if (tid < 512) hist[tid] = 0;

  // In-register scoring: 16 pixels/thread, p = e4*4096 + tid*4 + c.
  uint32_t uv[16];
  float    rv[16];
  const float4* rb4 = real4 + (size_t)b * (NPIX / 4);
#pragma unroll
  for (int e4 = 0; e4 < 4; ++e4) {
    float4 im = rb4[e4 * 1024 + tid];
    uint32_t base = (uint32_t)(b * NPIX + e4 * 4096) + (uint32_t)(tid << 2);
    rv[e4*4+0] = im.x; rv[e4*4+1] = im.y; rv[e4*4+2] = im.z; rv[e4*4+3] = im.w;
    uv[e4*4+0] = (im.x <= 0.99f) ? ((threefry_bits(base + 0u) >> 9) + 1u) : 0u;
    uv[e4*4+1] = (im.y <= 0.99f) ? ((threefry_bits(base + 1u) >> 9) + 1u) : 0u;
    uv[e4*4+2] = (im.z <= 0.99f) ? ((threefry_bits(base + 2u) >> 9) + 1u) : 0u;
    uv[e4*4+3] = (im.w <= 0.99f) ? ((threefry_bits(base + 3u) >> 9) + 1u) : 0u;
  }
  __syncthreads();

  // Histogram over uniform top-9 bits.
#pragma unroll
  for (int e = 0; e < 16; ++e)
    if (uv[e]) atomicAdd(&hist[(uv[e] - 1u) >> 14], 1u);
  __syncthreads();

  // Wave-parallel suffix scan over 512 buckets.
  uint32_t cnt = 0, sfx = 0;
  if (tid < 512) {
    cnt = hist[tid];
    sfx = cnt;
#pragma unroll
    for (int off = 1; off < 64; off <<= 1) {
      uint32_t u = __shfl_down(sfx, off, 64);
      if (lane + off < 64) sfx += u;
    }
    if (lane == 0) wt[wv] = sfx;
  }
  __syncthreads();
  if (tid < 8) {
    uint32_t t = wt[tid], s = t;
#pragma unroll
    for (int off = 1; off < 8; off <<= 1) {
      uint32_t u = __shfl_down(s, off, 64);
      if (tid + off < 8) s += u;
    }
    offs[tid] = s - t;
  }
  __syncthreads();
  if (tid < 512) {
    uint32_t tot = sfx + offs[wv];   // keys in buckets >= tid
    uint32_t above = tot - cnt;      // keys in buckets >  tid
    if (tot >= SAMPLE && above < SAMPLE && cnt > 0) {
      sh_bstar = (uint32_t)tid;
      sh_above = above;
    }
  }
  __syncthreads();
  const int bstar = (int)sh_bstar;
  const uint32_t kneed = SAMPLE - sh_above;

  float4* ob = pcl4 + (size_t)b * SAMPLE;
  auto emit = [&](int p, float depth01, uint32_t slot) {
    int i = p >> 7, j = p & 127;
    float tj = (2.0f * (float)j) / 127.0f - 1.0f;
    float ti = (2.0f * (float)i) / 127.0f - 1.0f;
    float u0 = (tj + 1.0f) * 64.0f;
    float u1 = (ti + 1.0f) * 64.0f;
    float d  = depth01 * sh_hb[2] + sh_c[2];
    float w0 = sh_minv[0]*u0 + sh_minv[1]*u1 + sh_minv[2];
    float w1 = sh_minv[3]*u0 + sh_minv[4]*u1 + sh_minv[5];
    float x = (w0 - 320.0f) * d / 588.03f;
    float y = (w1 - 240.0f) * d / 587.07f;
    float4 o;
    o.x = (x - sh_c[0]) / sh_hb[0];
    o.y = (y - sh_c[1]) / sh_hb[1];
    o.z = (d - sh_c[2]) / sh_hb[2];
    o.w = 0.0f;
    ob[slot] = o;
  };

  // Wave-ballot-aggregated compaction (1 atomic/wave per class per iter).
#pragma unroll
  for (int e = 0; e < 16; ++e) {
    uint32_t v = uv[e];
    int p = (e >> 2) * 4096 + (tid << 2) + (e & 3);
    int bk = v ? (int)((v - 1u) >> 14) : -1;
    bool hi = (bk > bstar);
    unsigned long long m = __ballot(hi);
    if (m) {
      int leader = __ffsll((unsigned long long)m) - 1;
      uint32_t base;
      if (lane == leader) base = atomicAdd(&sh_cnt, (uint32_t)__popcll(m));
      base = __shfl(base, leader, 64);
      if (hi) emit(p, rv[e], base + (uint32_t)__popcll(m & ((1ull << lane) - 1ull)));
    }
    bool eqb = (bk == bstar);
    unsigned long long m2 = __ballot(eqb);
    if (m2) {
      int leader = __ffsll((unsigned long long)m2) - 1;
      uint32_t cb;
      if (lane == leader) cb = atomicAdd(&sh_ccnt, (uint32_t)__popcll(m2));
      cb = __shfl(cb, leader, 64);
      if (eqb) {
        uint32_t ci = cb + (uint32_t)__popcll(m2 & ((1ull << lane) - 1ull));
        if (ci < 512) {
          cand[ci] = ((uint64_t)v << 14) | (uint64_t)(16383 - p);
          candrv[ci] = rv[e];
        }
      }
    }
  }
  __syncthreads();

  // Rank-select the kneed largest among the boundary-bucket candidates.
  uint32_t c = sh_ccnt; if (c > 512) c = 512;
  if (tid < 64) {
    for (uint32_t basei = 0; basei < c; basei += 64) {
      uint32_t i = basei + (uint32_t)lane;
      bool act = (i < c);
      uint64_t ki = act ? cand[i] : 0ull;
      uint32_t rank = 0;
      for (uint32_t j2 = 0; j2 < c; ++j2) rank += (cand[j2] > ki) ? 1u : 0u;
      bool sel = act && (rank < kneed);   // keys unique -> exactly kneed
      unsigned long long m = __ballot(sel);
      if (m) {
        int leader = __ffsll((unsigned long long)m) - 1;
        uint32_t base;
        if (lane == leader) base = atomicAdd(&sh_cnt, (uint32_t)__popcll(m));
        base = __shfl(base, leader, 64);
        if (sel) {
          int p = 16383 - (int)(ki & 0x3FFFull);
          emit(p, candrv[i], base + (uint32_t)__popcll(m & ((1ull << lane) - 1ull)));
        }
      }
    }
  }
}

// ---------------------------------------------------------------------------
// K2: chamfer sums, strength-reduced inner loop.
//   min_v (p-v)^2 = |p|^2 + min_v (|v|^2 - 2 p.v)
// LDS side staged as (-2x,-2y,-2z,|.|^2) -> inner pair = 3 chained fma + min.
// Blocks 0..511: dir A (8 point-groups of 128/batch, verts in LDS, 8-way
// vert split, 4 pts/thread). Blocks 512..959: dir B (7 vert-groups of
// 128/batch, points in LDS, 8-way point split, 4 verts/thread).
// Each block atomicAdds its pre-scaled partial into d_out[0].
// ---------------------------------------------------------------------------
#define NA_BLOCKS 512
#define NB_SLICES 7
#define NB_BLOCKS (BATCH * NB_SLICES)

__global__ __launch_bounds__(256, 4) void dist_kernel(
    const float* __restrict__ verts,
    const float4* __restrict__ pcl4,
    float* __restrict__ out) {
  __shared__ __align__(16) uint8_t shbuf[20992];
  __shared__ float red[4];
  const int blk = blockIdx.x;
  const int tid = threadIdx.x;
  const int s = tid >> 5;
  const int g = tid & 31;
  float val = 0.0f;

  if (blk < NA_BLOCKS) {
    const int b = blk >> 3, slice = blk & 7;
    float4* sv4 = (float4*)shbuf;                 // 778*16 = 12448 B
    float* pmin = (float*)(shbuf + 12448);        // 8*128*4 = 4096 B
    float* npl  = (float*)(shbuf + 16544);        // 128*4 = 512 B
    const float* vb = verts + (size_t)b * NV * 3;
    for (int v = tid; v < NV; v += 256) {
      float x = vb[v*3], y = vb[v*3+1], z = vb[v*3+2];
      float4 t;
      t.x = -2.0f*x; t.y = -2.0f*y; t.z = -2.0f*z; t.w = x*x + y*y + z*z;
      sv4[v] = t;
    }
    const float4* pb = pcl4 + (size_t)b * SAMPLE + slice * 128;
    float px[4], py[4], pz[4], np[4], mn[4];
#pragma unroll
    for (int j = 0; j < 4; ++j) {
      float4 q = pb[j * 32 + g];
      px[j] = q.x; py[j] = q.y; pz[j] = q.z;
      np[j] = q.x*q.x + q.y*q.y + q.z*q.z;
      mn[j] = INFINITY;
    }
    __syncthreads();
    const int vs = s * 98;
    const int ve = (vs + 98 < NV) ? vs + 98 : NV;
    for (int v = vs; v < ve; ++v) {
      float4 vv = sv4[v];                          // broadcast b128
#pragma unroll
      for (int j = 0; j < 4; ++j) {
        float t = fmaf(pz[j], vv.z, fmaf(py[j], vv.y, fmaf(px[j], vv.x, vv.w)));
        mn[j] = fminf(mn[j], t);
      }
    }
#pragma unroll
    for (int j = 0; j < 4; ++j) {
      pmin[s * 128 + j * 32 + g] = mn[j];
      if (s == 0) npl[j * 32 + g] = np[j];
    }
    __syncthreads();
    if (tid < 128) {
      float m = pmin[tid];
#pragma unroll
      for (int ss = 1; ss < 8; ++ss) m = fminf(m, pmin[ss * 128 + tid]);
      val = (m + npl[tid]) * A_SCALE;
    }
  } else {
    const int bb = blk - NA_BLOCKS;
    const int b = bb / NB_SLICES, slice = bb % NB_SLICES;
    float4* sp4 = (float4*)shbuf;                 // 1024*16 = 16384 B
    float* vmin = (float*)(shbuf + 16384);        // 4096 B
    float* nvl  = (float*)(shbuf + 20480);        // 512 B
    const float4* pcb = pcl4 + (size_t)b * SAMPLE;
    for (int i = tid; i < SAMPLE; i += 256) {
      float4 q = pcb[i];
      float4 t;
      t.x = -2.0f*q.x; t.y = -2.0f*q.y; t.z = -2.0f*q.z;
      t.w = q.x*q.x + q.y*q.y + q.z*q.z;
      sp4[i] = t;
    }
    const float* vb = verts + (size_t)b * NV * 3;
    const int vbase = slice * 128;
    float vx[4], vy[4], vz[4], nv[4], mn[4];
#pragma unroll
    for (int j = 0; j < 4; ++j) {
      int v = vbase + j * 32 + g;
      int vc = (v < NV) ? v : 0;
      vx[j] = vb[vc*3]; vy[j] = vb[vc*3+1]; vz[j] = vb[vc*3+2];
      nv[j] = vx[j]*vx[j] + vy[j]*vy[j] + vz[j]*vz[j];
      mn[j] = INFINITY;
    }
    __syncthreads();
    const int ps = s * 128;
    for (int i = 0; i < 128; ++i) {
      float4 pt = sp4[ps + i];                     // broadcast b128
#pragma unroll
      for (int j = 0; j < 4; ++j) {
        float t = fmaf(vz[j], pt.z, fmaf(vy[j], pt.y, fmaf(vx[j], pt.x, pt.w)));
        mn[j] = fminf(mn[j], t);
      }
    }
#pragma unroll
    for (int j = 0; j < 4; ++j) {
      vmin[s * 128 + j * 32 + g] = mn[j];
      if (s == 0) nvl[j * 32 + g] = nv[j];
    }
    __syncthreads();
    if (tid < 128 && (vbase + tid) < NV) {
      float m = vmin[tid];
#pragma unroll
      for (int ss = 1; ss < 8; ++ss) m = fminf(m, vmin[ss * 128 + tid]);
      val = (m + nvl[tid]) * B_SCALE;
    }
  }

  float r = waveReduceSum(val);
  if ((tid & 63) == 0) red[tid >> 6] = r;
  __syncthreads();
  if (tid == 0) atomicAdd(out, red[0] + red[1] + red[2] + red[3]);
}

extern "C" void kernel_launch(void* const* d_in, const int* in_sizes, int n_in,
                              void* d_out, int out_size, void* d_ws, size_t ws_size,
                              hipStream_t stream) {
  const float* real   = (const float*)d_in[0];
  // d_in[1] = synth (unused), d_in[3] = faces (unused)
  const float* verts  = (const float*)d_in[2];
  const float* center = (const float*)d_in[4];
  const float* M      = (const float*)d_in[5];
  const float* cube   = (const float*)d_in[6];

  float4* pcl4 = (float4*)d_ws;                    // 64*1024*16 B = 1 MiB
  float* out = (float*)d_out;

  select_kernel<<<dim3(BATCH), dim3(1024), 0, stream>>>(
      (const float4*)real, center, M, cube, pcl4, out);
  dist_kernel<<<dim3(NA_BLOCKS + NB_BLOCKS), dim3(256), 0, stream>>>(
      verts, pcl4, out);
}